// Round 10
// baseline (517.113 us; speedup 1.0000x reference)
//
#include <hip/hip_runtime.h>
#include <hip/hip_bf16.h>

typedef __bf16 bf16;
typedef __attribute__((ext_vector_type(8)))  __bf16 bf16x8;
typedef __attribute__((ext_vector_type(4)))  __bf16 bf16x4;
typedef __attribute__((ext_vector_type(4)))  float  f32x4;

#define SEQ   2048
#define NDIM  256
#define NH3   48
#define CH    64
#define SQS   72     // sQ row stride (pad: rows advance 4 banks)
#define SPS   72     // sP row stride
#define VTS   2176   // g_vt row stride (4352B = 17 x 256B sectors)

// canonical bf16 input arena offsets (elements; multiples of 8 -> 16B aligned)
#define OFF_NODES 0
#define OFF_POS   524288
#define OFF_ROT   536576
#define OFF_WN    544768
#define OFF_BN    1069056
#define OFF_WP    1071104
#define OFF_BP    1083392
#define OFF_WR    1085440
#define OFF_WV    1093632
#define OFF_BV    4239360
#define TOT_IN    4251648

__device__ bf16 g_in[TOT_IN];              // 8.5 MB canonical bf16 inputs
__device__ bf16 g_k [NH3 * SEQ * CH];      // [h][s][c] 12.6 MB
__device__ bf16 g_q [NH3 * SEQ * CH];      // [h][s][c] 12.6 MB
__device__ bf16 g_vt[NH3 * NDIM * VTS];    // [h][d][j'] padded rows, j-permuted per 64-block
__device__ int  g_isf32;

// ---------------------------------------------------------------- dtype probe
__global__ __launch_bounds__(256) void detect_k(const unsigned short* __restrict__ p) {
    __shared__ int cff, czero;
    if (threadIdx.x == 0) { cff = 0; czero = 0; }
    __syncthreads();
    int ff = 0, zz = 0;
    for (int r = 0; r < 64; ++r) {
        int idx = threadIdx.x * 64 + r;
        unsigned short u = p[idx];
        if (((u >> 7) & 0xFF) == 0xFF) ff++;
        if (((idx & 1) == 0) && (u == 0)) zz++;
    }
    if (ff) atomicAdd(&cff, ff);
    if (zz) atomicAdd(&czero, zz);
    __syncthreads();
    if (threadIdx.x == 0) g_isf32 = (cff > 2 || czero > 6000) ? 1 : 0;
}

// --------------------------------------------------------- input canonicalize
__global__ __launch_bounds__(256) void convert_k(
    const void* s0, const void* s1, const void* s2, const void* s3, const void* s4,
    const void* s5, const void* s6, const void* s7, const void* s8, const void* s9)
{
    const void* srcs[10] = {s0, s1, s2, s3, s4, s5, s6, s7, s8, s9};
    const int   szs[10]  = {524288, 12288, 8192, 524288, 2048, 12288, 2048, 8192, 3145728, 12288};
    const int   offs[10] = {OFF_NODES, OFF_POS, OFF_ROT, OFF_WN, OFF_BN,
                            OFF_WP, OFF_BP, OFF_WR, OFF_WV, OFF_BV};
    const int y = blockIdx.y;
    const void* src = srcs[y];
    bf16* dst = g_in + offs[y];
    const int n = szs[y];
    const int isf = g_isf32;
    const int stride = gridDim.x * 256 * 4;
    for (int i = (blockIdx.x * 256 + threadIdx.x) * 4; i < n; i += stride) {
        bf16x4 o;
        if (isf) {
            float4 v = *(const float4*)((const float*)src + i);
            o[0] = (bf16)v.x; o[1] = (bf16)v.y; o[2] = (bf16)v.z; o[3] = (bf16)v.w;
        } else {
            o = *(const bf16x4*)((const bf16*)src + i);
        }
        *(bf16x4*)(dst + i) = o;
    }
}

// ------------------------------------------------- nodes -> k,q (heads 0-15)
__global__ __launch_bounds__(256) void proj_nodes_kq()
{
    __shared__ __align__(16) bf16 sB[64 * 264];
    const bf16* nodes = g_in + OFF_NODES;
    const bf16* Wn    = g_in + OFF_WN;
    const bf16* bn    = g_in + OFF_BN;
    const int t  = threadIdx.x;
    const int s0 = blockIdx.x * 64;
    const int f0 = blockIdx.y * 64;

    for (int rep = 0; rep < 8; ++rep) {
        int idx = t + rep * 256;
        int row = idx >> 5, chunk = idx & 31;
        *(bf16x8*)&sB[row * 264 + chunk * 8] =
            *(const bf16x8*)&Wn[(f0 + row) * 256 + chunk * 8];
    }
    __syncthreads();

    const int w = t >> 6, lane = t & 63;
    const int l15 = lane & 15, quad = lane >> 4;

    f32x4 acc[4] = {{}, {}, {}, {}};
    const bf16* arow = nodes + (s0 + w * 16 + l15) * 256 + quad * 8;
#pragma unroll
    for (int kc = 0; kc < 8; ++kc) {
        bf16x8 af = *(const bf16x8*)(arow + kc * 32);
#pragma unroll
        for (int ft = 0; ft < 4; ++ft) {
            bf16x8 bfr = *(const bf16x8*)&sB[(ft * 16 + l15) * 264 + kc * 32 + quad * 8];
            acc[ft] = __builtin_amdgcn_mfma_f32_16x16x32_bf16(af, bfr, acc[ft], 0, 0, 0);
        }
    }
#pragma unroll
    for (int ft = 0; ft < 4; ++ft) {
        int f = f0 + ft * 16 + l15;
        float bias = (float)bn[f];
        int h = f >> 7, c2 = f & 127;
        bf16* base = (c2 < 64) ? (g_k + h * SEQ * CH + c2)
                               : (g_q + h * SEQ * CH + (c2 - 64));
#pragma unroll
        for (int r = 0; r < 4; ++r) {
            int s = s0 + w * 16 + quad * 4 + r;
            base[s * CH] = (bf16)(acc[ft][r] + bias);
        }
    }
}

// ------------------------------------- pos/rot -> k,q (heads 16-31 / 32-47)
__global__ __launch_bounds__(256) void proj_posrot_kq()
{
    const bf16* pos  = g_in + OFF_POS;
    const bf16* rotq = g_in + OFF_ROT;
    const bf16* Wp   = g_in + OFF_WP;
    const bf16* bp   = g_in + OFF_BP;
    const bf16* Wr   = g_in + OFF_WR;
    int id = blockIdx.x * 256 + threadIdx.x;
    int f  = id & 2047;
    int s  = (id >> 11) & 2047;
    int src = id >> 22;
    float y; int h;
    if (src == 0) {
        float a = (float)bp[f];
#pragma unroll
        for (int x = 0; x < 6; ++x) a += (float)pos[s * 6 + x] * (float)Wp[f * 6 + x];
        y = a; h = 16 + (f >> 7);
    } else {
        float a = 0.f;
#pragma unroll
        for (int x = 0; x < 4; ++x) a += (float)rotq[s * 4 + x] * (float)Wr[f * 4 + x];
        y = a; h = 32 + (f >> 7);
    }
    int c2 = f & 127;
    if (c2 < 64) g_k[(h * SEQ + s) * CH + c2]        = (bf16)y;
    else         g_q[(h * SEQ + s) * CH + (c2 - 64)] = (bf16)y;
}

// ----------------------- nodes -> V (transposed + j-permuted, padded stride)
__global__ __launch_bounds__(256) void proj_v()
{
    __shared__ __align__(16) bf16 sB[64 * 264];
    __shared__ __align__(16) bf16 sO[64 * 72];
    const bf16* nodes = g_in + OFF_NODES;
    const bf16* Wv    = g_in + OFF_WV;
    const bf16* bv    = g_in + OFF_BV;
    const int t  = threadIdx.x;
    const int s0 = blockIdx.x * 64;
    const int f0 = blockIdx.y * 64;

    for (int rep = 0; rep < 8; ++rep) {
        int idx = t + rep * 256;
        int row = idx >> 5, chunk = idx & 31;
        *(bf16x8*)&sB[row * 264 + chunk * 8] =
            *(const bf16x8*)&Wv[(f0 + row) * 256 + chunk * 8];
    }
    __syncthreads();

    const int w = t >> 6, lane = t & 63;
    const int l15 = lane & 15, quad = lane >> 4;

    f32x4 acc[4] = {{}, {}, {}, {}};
    const bf16* arow = nodes + (s0 + w * 16 + l15) * 256 + quad * 8;
#pragma unroll
    for (int kc = 0; kc < 8; ++kc) {
        bf16x8 af = *(const bf16x8*)(arow + kc * 32);
#pragma unroll
        for (int ft = 0; ft < 4; ++ft) {
            bf16x8 bfr = *(const bf16x8*)&sB[(ft * 16 + l15) * 264 + kc * 32 + quad * 8];
            acc[ft] = __builtin_amdgcn_mfma_f32_16x16x32_bf16(af, bfr, acc[ft], 0, 0, 0);
        }
    }
    __syncthreads();
#pragma unroll
    for (int ft = 0; ft < 4; ++ft) {
        int n = f0 + ft * 16 + l15;
        float bias = (float)bv[n];
#pragma unroll
        for (int r = 0; r < 4; ++r) {
            // s-local l = w*16+quad*4+r -> j' = (quad*4+r)*4 + w
            sO[(ft * 16 + l15) * 72 + (quad * 4 + r) * 4 + w] = (bf16)(acc[ft][r] + bias);
        }
    }
    __syncthreads();
    for (int rep = 0; rep < 2; ++rep) {
        int idx = t + rep * 256;
        int row = idx >> 3, chunk = idx & 7;
        *(bf16x8*)&g_vt[(size_t)(f0 + row) * VTS + s0 + chunk * 8] =
            *(const bf16x8*)&sO[row * 72 + chunk * 8];
    }
}

// ---------------------------------------------------------------- zero d_out
__global__ __launch_bounds__(256) void zero_out_k(float* __restrict__ out) {
    int idx = (blockIdx.x * 256 + threadIdx.x) * 4;
    f32x4 z = {0.f, 0.f, 0.f, 0.f};
    *(f32x4*)&out[idx] = z;
}

// ------------------------------------------------------------- attention
// 256 threads (4 waves), Bi=64, grid 1536. XCD head-clustering (6 heads/XCD).
// Key dataflow: V never touches LDS (wave = d-quarter owns ALL 64 i, so each
// V byte is used by exactly one wave -> register-direct 16-row gathers, every
// fetched 64B line fully consumed). LDS = double-buffered sQ + sP only
// (28KB). 2 barriers/step. Global loads issued a phase before their use so
// the compiler's pre-barrier vmcnt(0) drain lands AFTER they're hidden.
__global__ __launch_bounds__(256, 4) void attn_k(float* __restrict__ out)
{
    const int bx  = blockIdx.x;
    const int xcd = bx & 7;
    const int sub = bx >> 3;             // 0..191
    const int h   = xcd * 6 + (sub % 6); // 6 heads per XCD
    const int it  = sub / 6;             // 0..31
    const int i0  = it * 64;
    const int t   = threadIdx.x;
    const int w   = t >> 6, lane = t & 63;
    const int l15 = lane & 15, quad = lane >> 4;
    const bool rot = (h >= 32);

    __shared__ __align__(16) bf16 sQ[2][64 * SQS];   // 2 x 9216 B
    __shared__ __align__(16) bf16 sP[64 * SPS];      // 9216 B
    __shared__ float sL[64];

    const bf16* kb = g_k  + h * SEQ * CH;
    const bf16* qb = g_q  + h * SEQ * CH;
    const bf16* vb = g_vt + (size_t)h * NDIM * VTS;

    // K fragments: wave w owns S-rows i0 + w*16 .. +16 (held all kernel)
    bf16x8 kf0 = *(const bf16x8*)&kb[(i0 + w * 16 + l15) * CH + quad * 8];
    bf16x8 kf1 = *(const bf16x8*)&kb[(i0 + w * 16 + l15) * CH + 32 + quad * 8];

    // V gather offsets: wave w = d-quarter
    int vo[4];
#pragma unroll
    for (int dt = 0; dt < 4; ++dt) vo[dt] = (w * 64 + dt * 16 + l15) * VTS + quad * 8;

    // Q staging decomposition: 512 16B-chunks, 2 per thread
    const int r0 = t >> 3, c0 = t & 7;           // chunk idx t
    const int r1 = (t + 256) >> 3;               // chunk idx t+256 (same c0)

    f32x4 acc[4][4];
#pragma unroll
    for (int a = 0; a < 4; ++a)
#pragma unroll
        for (int b = 0; b < 4; ++b) acc[a][b] = (f32x4){0.f, 0.f, 0.f, 0.f};
    f32x4 lp = {0.f, 0.f, 0.f, 0.f};

    // pre-stage Q step 0 into sQ[0]
    {
        bf16x8 a = *(const bf16x8*)&qb[t * 8];
        bf16x8 c = *(const bf16x8*)&qb[(t + 256) * 8];
        *(bf16x8*)&sQ[0][r0 * SQS + c0 * 8] = a;
        *(bf16x8*)&sQ[0][r1 * SQS + c0 * 8] = c;
    }
    __syncthreads();

    for (int st = 0; st < 32; ++st) {
        const int b = st & 1;

        // ---- stage NEXT Q into the idle buffer (coalesced; latency at top)
        if (st < 31) {
            const bf16* qn = qb + (st + 1) * 4096;
            bf16x8 a = *(const bf16x8*)&qn[t * 8];
            bf16x8 c = *(const bf16x8*)&qn[(t + 256) * 8];
            *(bf16x8*)&sQ[b ^ 1][r0 * SQS + c0 * 8] = a;
            *(bf16x8*)&sQ[b ^ 1][r1 * SQS + c0 * 8] = c;
        }

        // ---- issue this step's V kc0 gathers (hidden behind S+P)
        const bf16* vbj = vb + st * 64;
        bf16x8 vf0[4];
#pragma unroll
        for (int dt = 0; dt < 4; ++dt) vf0[dt] = *(const bf16x8*)&vbj[vo[dt]];

        // ---- S phase: 16 i-rows x 64 j per wave (from sQ[b])
        const bf16* sq = sQ[b];
        f32x4 sjb[4];
#pragma unroll
        for (int jb = 0; jb < 4; ++jb) {
            bf16x8 q0 = *(const bf16x8*)&sq[(jb * 16 + l15) * SQS + quad * 8];
            bf16x8 q1 = *(const bf16x8*)&sq[(jb * 16 + l15) * SQS + 32 + quad * 8];
            f32x4 sa = {};
            sa = __builtin_amdgcn_mfma_f32_16x16x32_bf16(kf0, q0, sa, 0, 0, 0);
            sa = __builtin_amdgcn_mfma_f32_16x16x32_bf16(kf1, q1, sa, 0, 0, 0);
            sjb[jb] = sa;
        }

        // ---- P phase: exp + pack; column j' = l15*4 + jb (logical j = jb*16+l15)
#pragma unroll
        for (int r = 0; r < 4; ++r) {
            bf16x4 pk;
#pragma unroll
            for (int jb = 0; jb < 4; ++jb) {
                float d = sjb[jb][r];
                float x = rot ? (d * d * 0.25f) : (d * 0.25f);
                x = fminf(x, 60.f);
                float p = __expf(x);
                lp[r] += p;
                pk[jb] = (bf16)p;
            }
            *(bf16x4*)&sP[(w * 16 + quad * 4 + r) * SPS + l15 * 4] = pk;
        }
        __syncthreads();                               // B_A: sP visible

        // ---- issue V kc1 (hidden behind PV kc0)
        bf16x8 vf1[4];
#pragma unroll
        for (int dt = 0; dt < 4; ++dt) vf1[dt] = *(const bf16x8*)&vbj[vo[dt] + 32];

        // ---- PV: wave w = d-quarter, ALL 64 i rows
        bf16x8 ap[4];
#pragma unroll
        for (int itr = 0; itr < 4; ++itr)
            ap[itr] = *(const bf16x8*)&sP[(itr * 16 + l15) * SPS + quad * 8];
#pragma unroll
        for (int itr = 0; itr < 4; ++itr)
#pragma unroll
            for (int dt = 0; dt < 4; ++dt)
                acc[itr][dt] = __builtin_amdgcn_mfma_f32_16x16x32_bf16(
                    ap[itr], vf0[dt], acc[itr][dt], 0, 0, 0);
#pragma unroll
        for (int itr = 0; itr < 4; ++itr)
            ap[itr] = *(const bf16x8*)&sP[(itr * 16 + l15) * SPS + 32 + quad * 8];
#pragma unroll
        for (int itr = 0; itr < 4; ++itr)
#pragma unroll
            for (int dt = 0; dt < 4; ++dt)
                acc[itr][dt] = __builtin_amdgcn_mfma_f32_16x16x32_bf16(
                    ap[itr], vf1[dt], acc[itr][dt], 0, 0, 0);
        __syncthreads();                               // B_B: sP reuse + sQ next visible
    }

    // l reduce across the 16 j-lanes (wave w owns S-rows w*16..+16)
#pragma unroll
    for (int off = 1; off < 16; off <<= 1) {
#pragma unroll
        for (int r = 0; r < 4; ++r) lp[r] += __shfl_xor(lp[r], off, 64);
    }
    if (l15 == 0) *(f32x4*)&sL[w * 16 + quad * 4] = lp;
    __syncthreads();

    // normalize + accumulate over heads into f32 output
#pragma unroll
    for (int itr = 0; itr < 4; ++itr) {
        f32x4 lv = *(const f32x4*)&sL[itr * 16 + quad * 4];
#pragma unroll
        for (int r = 0; r < 4; ++r) {
            float inv = 1.0f / lv[r];
            float* ob = &out[(i0 + itr * 16 + quad * 4 + r) * NDIM + w * 64 + l15];
#pragma unroll
            for (int dt = 0; dt < 4; ++dt)
                atomicAdd(ob + dt * 16, acc[itr][dt][r] * inv);
        }
    }
}

extern "C" void kernel_launch(void* const* d_in, const int* in_sizes, int n_in,
                              void* d_out, int out_size, void* d_ws, size_t ws_size,
                              hipStream_t stream) {
    detect_k <<<dim3(1),        dim3(256), 0, stream>>>((const unsigned short*)d_in[8]);
    convert_k<<<dim3(768, 10),  dim3(256), 0, stream>>>(d_in[0], d_in[1], d_in[2], d_in[3],
                                                        d_in[4], d_in[5], d_in[6], d_in[7],
                                                        d_in[8], d_in[9]);
    proj_nodes_kq <<<dim3(32, 32),  dim3(256), 0, stream>>>();
    proj_posrot_kq<<<dim3(32768),   dim3(256), 0, stream>>>();
    proj_v        <<<dim3(32, 192), dim3(256), 0, stream>>>();
    zero_out_k    <<<dim3(512),     dim3(256), 0, stream>>>((float*)d_out);
    attn_k        <<<dim3(1536),    dim3(256), 0, stream>>>((float*)d_out);
}

// Round 11
// 384.930 us; speedup vs baseline: 1.3434x; 1.3434x over previous
//
#include <hip/hip_runtime.h>
#include <hip/hip_bf16.h>

typedef __bf16 bf16;
typedef __attribute__((ext_vector_type(8)))  __bf16 bf16x8;
typedef __attribute__((ext_vector_type(4)))  __bf16 bf16x4;
typedef __attribute__((ext_vector_type(4)))  float  f32x4;

#define SEQ   2048
#define NDIM  256
#define NH3   48
#define CH    64
#define SQS   72     // sQ row stride (pad: rows advance 4 banks)
#define SVS   72     // sV row stride
#define SPS   72     // sP row stride
#define VTS   2176   // g_vt row stride (4352B = 17 x 256B sectors)

// canonical bf16 input arena offsets (elements; multiples of 8 -> 16B aligned)
#define OFF_NODES 0
#define OFF_POS   524288
#define OFF_ROT   536576
#define OFF_WN    544768
#define OFF_BN    1069056
#define OFF_WP    1071104
#define OFF_BP    1083392
#define OFF_WR    1085440
#define OFF_WV    1093632
#define OFF_BV    4239360
#define TOT_IN    4251648

__device__ bf16  g_in[TOT_IN];              // 8.5 MB canonical bf16 inputs
__device__ bf16  g_k [NH3 * SEQ * CH];      // [h][s][c] 12.6 MB
__device__ bf16  g_q [NH3 * SEQ * CH];      // [h][s][c] 12.6 MB
__device__ bf16  g_vt[NH3 * NDIM * VTS];    // [h][d][j'] padded, j-permuted per 64-block
__device__ float g_part[(size_t)NH3 * SEQ * NDIM];  // 100 MB per-head partials (no atomics)
__device__ int   g_isf32;

// ---------------------------------------------------------------- dtype probe
__global__ __launch_bounds__(256) void detect_k(const unsigned short* __restrict__ p) {
    __shared__ int cff, czero;
    if (threadIdx.x == 0) { cff = 0; czero = 0; }
    __syncthreads();
    int ff = 0, zz = 0;
    for (int r = 0; r < 64; ++r) {
        int idx = threadIdx.x * 64 + r;
        unsigned short u = p[idx];
        if (((u >> 7) & 0xFF) == 0xFF) ff++;
        if (((idx & 1) == 0) && (u == 0)) zz++;
    }
    if (ff) atomicAdd(&cff, ff);
    if (zz) atomicAdd(&czero, zz);
    __syncthreads();
    if (threadIdx.x == 0) g_isf32 = (cff > 2 || czero > 6000) ? 1 : 0;
}

// --------------------------------------------------------- input canonicalize
__global__ __launch_bounds__(256) void convert_k(
    const void* s0, const void* s1, const void* s2, const void* s3, const void* s4,
    const void* s5, const void* s6, const void* s7, const void* s8, const void* s9)
{
    const void* srcs[10] = {s0, s1, s2, s3, s4, s5, s6, s7, s8, s9};
    const int   szs[10]  = {524288, 12288, 8192, 524288, 2048, 12288, 2048, 8192, 3145728, 12288};
    const int   offs[10] = {OFF_NODES, OFF_POS, OFF_ROT, OFF_WN, OFF_BN,
                            OFF_WP, OFF_BP, OFF_WR, OFF_WV, OFF_BV};
    const int y = blockIdx.y;
    const void* src = srcs[y];
    bf16* dst = g_in + offs[y];
    const int n = szs[y];
    const int isf = g_isf32;
    const int stride = gridDim.x * 256 * 4;
    for (int i = (blockIdx.x * 256 + threadIdx.x) * 4; i < n; i += stride) {
        bf16x4 o;
        if (isf) {
            float4 v = *(const float4*)((const float*)src + i);
            o[0] = (bf16)v.x; o[1] = (bf16)v.y; o[2] = (bf16)v.z; o[3] = (bf16)v.w;
        } else {
            o = *(const bf16x4*)((const bf16*)src + i);
        }
        *(bf16x4*)(dst + i) = o;
    }
}

// ------------------------------------------------- nodes -> k,q (heads 0-15)
__global__ __launch_bounds__(256) void proj_nodes_kq()
{
    __shared__ __align__(16) bf16 sB[64 * 264];
    const bf16* nodes = g_in + OFF_NODES;
    const bf16* Wn    = g_in + OFF_WN;
    const bf16* bn    = g_in + OFF_BN;
    const int t  = threadIdx.x;
    const int s0 = blockIdx.x * 64;
    const int f0 = blockIdx.y * 64;

    for (int rep = 0; rep < 8; ++rep) {
        int idx = t + rep * 256;
        int row = idx >> 5, chunk = idx & 31;
        *(bf16x8*)&sB[row * 264 + chunk * 8] =
            *(const bf16x8*)&Wn[(f0 + row) * 256 + chunk * 8];
    }
    __syncthreads();

    const int w = t >> 6, lane = t & 63;
    const int l15 = lane & 15, quad = lane >> 4;

    f32x4 acc[4] = {{}, {}, {}, {}};
    const bf16* arow = nodes + (s0 + w * 16 + l15) * 256 + quad * 8;
#pragma unroll
    for (int kc = 0; kc < 8; ++kc) {
        bf16x8 af = *(const bf16x8*)(arow + kc * 32);
#pragma unroll
        for (int ft = 0; ft < 4; ++ft) {
            bf16x8 bfr = *(const bf16x8*)&sB[(ft * 16 + l15) * 264 + kc * 32 + quad * 8];
            acc[ft] = __builtin_amdgcn_mfma_f32_16x16x32_bf16(af, bfr, acc[ft], 0, 0, 0);
        }
    }
#pragma unroll
    for (int ft = 0; ft < 4; ++ft) {
        int f = f0 + ft * 16 + l15;
        float bias = (float)bn[f];
        int h = f >> 7, c2 = f & 127;
        bf16* base = (c2 < 64) ? (g_k + h * SEQ * CH + c2)
                               : (g_q + h * SEQ * CH + (c2 - 64));
#pragma unroll
        for (int r = 0; r < 4; ++r) {
            int s = s0 + w * 16 + quad * 4 + r;
            base[s * CH] = (bf16)(acc[ft][r] + bias);
        }
    }
}

// ----------------- pos/rot -> k,q (heads 16-31 / 32-47), 4 outputs per thread
__global__ __launch_bounds__(256) void proj_posrot_kq()
{
    const bf16* pos  = g_in + OFF_POS;
    const bf16* rotq = g_in + OFF_ROT;
    const bf16* Wp   = g_in + OFF_WP;
    const bf16* bp   = g_in + OFF_BP;
    const bf16* Wr   = g_in + OFF_WR;
    int id = blockIdx.x * 256 + threadIdx.x;  // 2 * 2048 * 512
    int fg  = id & 511;                        // f-group of 4
    int s   = (id >> 9) & 2047;
    int src = id >> 20;
    int f0  = fg * 4;
    float y[4]; int h;
    if (src == 0) {
#pragma unroll
        for (int j = 0; j < 4; ++j) {
            float a = (float)bp[f0 + j];
#pragma unroll
            for (int x = 0; x < 6; ++x)
                a += (float)pos[s * 6 + x] * (float)Wp[(f0 + j) * 6 + x];
            y[j] = a;
        }
        h = 16 + (f0 >> 7);
    } else {
#pragma unroll
        for (int j = 0; j < 4; ++j) {
            float a = 0.f;
#pragma unroll
            for (int x = 0; x < 4; ++x)
                a += (float)rotq[s * 4 + x] * (float)Wr[(f0 + j) * 4 + x];
            y[j] = a;
        }
        h = 32 + (f0 >> 7);
    }
    bf16x4 o;
#pragma unroll
    for (int j = 0; j < 4; ++j) o[j] = (bf16)y[j];
    int c2 = f0 & 127;
    if (c2 < 64) *(bf16x4*)&g_k[(h * SEQ + s) * CH + c2]        = o;
    else         *(bf16x4*)&g_q[(h * SEQ + s) * CH + (c2 - 64)] = o;
}

// ----------------------- nodes -> V (transposed + j-permuted, padded stride)
__global__ __launch_bounds__(256) void proj_v()
{
    __shared__ __align__(16) bf16 sB[64 * 264];
    __shared__ __align__(16) bf16 sO[64 * 72];
    const bf16* nodes = g_in + OFF_NODES;
    const bf16* Wv    = g_in + OFF_WV;
    const bf16* bv    = g_in + OFF_BV;
    const int t  = threadIdx.x;
    const int s0 = blockIdx.x * 64;
    const int f0 = blockIdx.y * 64;

    for (int rep = 0; rep < 8; ++rep) {
        int idx = t + rep * 256;
        int row = idx >> 5, chunk = idx & 31;
        *(bf16x8*)&sB[row * 264 + chunk * 8] =
            *(const bf16x8*)&Wv[(f0 + row) * 256 + chunk * 8];
    }
    __syncthreads();

    const int w = t >> 6, lane = t & 63;
    const int l15 = lane & 15, quad = lane >> 4;

    f32x4 acc[4] = {{}, {}, {}, {}};
    const bf16* arow = nodes + (s0 + w * 16 + l15) * 256 + quad * 8;
#pragma unroll
    for (int kc = 0; kc < 8; ++kc) {
        bf16x8 af = *(const bf16x8*)(arow + kc * 32);
#pragma unroll
        for (int ft = 0; ft < 4; ++ft) {
            bf16x8 bfr = *(const bf16x8*)&sB[(ft * 16 + l15) * 264 + kc * 32 + quad * 8];
            acc[ft] = __builtin_amdgcn_mfma_f32_16x16x32_bf16(af, bfr, acc[ft], 0, 0, 0);
        }
    }
    __syncthreads();
#pragma unroll
    for (int ft = 0; ft < 4; ++ft) {
        int n = f0 + ft * 16 + l15;
        float bias = (float)bv[n];
#pragma unroll
        for (int r = 0; r < 4; ++r) {
            // s-local l = w*16+quad*4+r -> j' = (quad*4+r)*4 + w
            sO[(ft * 16 + l15) * 72 + (quad * 4 + r) * 4 + w] = (bf16)(acc[ft][r] + bias);
        }
    }
    __syncthreads();
    for (int rep = 0; rep < 2; ++rep) {
        int idx = t + rep * 256;
        int row = idx >> 3, chunk = idx & 7;
        *(bf16x8*)&g_vt[(size_t)(f0 + row) * VTS + s0 + chunk * 8] =
            *(const bf16x8*)&sO[row * 72 + chunk * 8];
    }
}

// ------------------------------------------------------------- attention
// R8 structure: 512 threads (8 waves), Bi=128, XCD head-clustering (6 heads
// per XCD). Per step: coalesced global->reg->LDS staging of Q(8KB)+V(32KB),
// S from sQ (K in regs), P into sP, PV from sP+sV. 3 barriers/step.
// Changes vs R8: padded LDS strides (72) to kill 16-row read aliasing;
// output via PLAIN stores to a per-head partial plane (no atomics).
__global__ __launch_bounds__(512, 4) void attn_k()
{
    const int bx  = blockIdx.x;
    const int xcd = bx & 7;
    const int sub = bx >> 3;             // 0..95
    const int h   = xcd * 6 + (sub % 6); // 6 heads per XCD
    const int it  = sub / 6;             // 0..15
    const int i0  = it * 128;
    const int t   = threadIdx.x;
    const int w   = t >> 6, lane = t & 63;
    const int l15 = lane & 15, quad = lane >> 4;
    const bool rot = (h >= 32);

    __shared__ __align__(16) bf16 sQ[64 * SQS];      //  9216 B
    __shared__ __align__(16) bf16 sV[256 * SVS];     // 36864 B
    __shared__ __align__(16) bf16 sP[128 * SPS];     // 18432 B
    __shared__ float sL[128];                        //   512 B (total 65024)

    const bf16* kb = g_k  + h * SEQ * CH;
    const bf16* qb = g_q  + h * SEQ * CH;
    const bf16* vb = g_vt + (size_t)h * NDIM * VTS;

    // K fragments: wave w owns S-rows i0 + w*16 .. +16
    bf16x8 kf0 = *(const bf16x8*)&kb[(i0 + w * 16 + l15) * CH + quad * 8];
    bf16x8 kf1 = *(const bf16x8*)&kb[(i0 + w * 16 + l15) * CH + 32 + quad * 8];

    // PV split: i-half ih = w>>2 (64 rows), d-quarter dq = w&3 (64 cols)
    const int ih = w >> 2, dq = w & 3;

    f32x4 acc[4][4];
#pragma unroll
    for (int a = 0; a < 4; ++a)
#pragma unroll
        for (int b = 0; b < 4; ++b) acc[a][b] = (f32x4){0.f, 0.f, 0.f, 0.f};
    f32x4 lp = {0.f, 0.f, 0.f, 0.f};

    for (int st = 0; st < 32; ++st) {
        // ---- stage Q (contiguous 8KB) + V (128B row segments), coalesced
        {
            int row = t >> 3, ch = t & 7;
            *(bf16x8*)&sQ[row * SQS + ch * 8] = *(const bf16x8*)&qb[st * 4096 + t * 8];
#pragma unroll
            for (int rep = 0; rep < 4; ++rep) {
                int idx = t + rep * 512;
                int vr = idx >> 3, vc = idx & 7;
                *(bf16x8*)&sV[vr * SVS + vc * 8] =
                    *(const bf16x8*)&vb[(size_t)vr * VTS + st * 64 + vc * 8];
            }
        }
        __syncthreads();                               // B1: staging visible

        // ---- S phase: 16 i-rows x 64 j per wave
        f32x4 sjb[4];
#pragma unroll
        for (int jb = 0; jb < 4; ++jb) {
            bf16x8 q0 = *(const bf16x8*)&sQ[(jb * 16 + l15) * SQS + quad * 8];
            bf16x8 q1 = *(const bf16x8*)&sQ[(jb * 16 + l15) * SQS + 32 + quad * 8];
            f32x4 sa = {};
            sa = __builtin_amdgcn_mfma_f32_16x16x32_bf16(kf0, q0, sa, 0, 0, 0);
            sa = __builtin_amdgcn_mfma_f32_16x16x32_bf16(kf1, q1, sa, 0, 0, 0);
            sjb[jb] = sa;
        }

        // ---- P phase: exp + pack; column j' = l15*4 + jb (logical j = jb*16+l15)
#pragma unroll
        for (int r = 0; r < 4; ++r) {
            bf16x4 pk;
#pragma unroll
            for (int jb = 0; jb < 4; ++jb) {
                float d = sjb[jb][r];
                float x = rot ? (d * d * 0.25f) : (d * 0.25f);
                x = fminf(x, 60.f);
                float p = __expf(x);
                lp[r] += p;
                pk[jb] = (bf16)p;
            }
            *(bf16x4*)&sP[(w * 16 + quad * 4 + r) * SPS + l15 * 4] = pk;
        }
        __syncthreads();                               // B2: sP visible

        // ---- PV phase: wave w owns (ih, dq): 64 i x 64 d
#pragma unroll
        for (int kc = 0; kc < 2; ++kc) {
            bf16x8 ap[4], vf[4];
#pragma unroll
            for (int itr = 0; itr < 4; ++itr)
                ap[itr] = *(const bf16x8*)&sP[(ih * 64 + itr * 16 + l15) * SPS + kc * 32 + quad * 8];
#pragma unroll
            for (int dt = 0; dt < 4; ++dt)
                vf[dt] = *(const bf16x8*)&sV[(dq * 64 + dt * 16 + l15) * SVS + kc * 32 + quad * 8];
#pragma unroll
            for (int itr = 0; itr < 4; ++itr)
#pragma unroll
                for (int dt = 0; dt < 4; ++dt)
                    acc[itr][dt] = __builtin_amdgcn_mfma_f32_16x16x32_bf16(
                        ap[itr], vf[dt], acc[itr][dt], 0, 0, 0);
        }
        __syncthreads();                               // B3: PV done reading
    }

    // l reduce across the 16 j-lanes (wave w owns S-rows w*16..+16)
#pragma unroll
    for (int off = 1; off < 16; off <<= 1) {
#pragma unroll
        for (int r = 0; r < 4; ++r) lp[r] += __shfl_xor(lp[r], off, 64);
    }
    if (l15 == 0) *(f32x4*)&sL[w * 16 + quad * 4] = lp;
    __syncthreads();

    // normalize + plain stores into this head's private partial plane
    float* pb = g_part + (size_t)h * SEQ * NDIM;
#pragma unroll
    for (int itr = 0; itr < 4; ++itr) {
        f32x4 lv = *(const f32x4*)&sL[ih * 64 + itr * 16 + quad * 4];
#pragma unroll
        for (int r = 0; r < 4; ++r) {
            float inv = 1.0f / lv[r];
            float* ob = &pb[(size_t)(i0 + ih * 64 + itr * 16 + quad * 4 + r) * NDIM + dq * 64 + l15];
#pragma unroll
            for (int dt = 0; dt < 4; ++dt)
                ob[dt * 16] = acc[itr][dt][r] * inv;
        }
    }
}

// ------------------------------------------- finalize: sum 48 head planes
__global__ __launch_bounds__(256) void finalize_k(float* __restrict__ out) {
    int idx = (blockIdx.x * 256 + threadIdx.x) * 4;
    f32x4 s = {0.f, 0.f, 0.f, 0.f};
#pragma unroll
    for (int hh = 0; hh < NH3; ++hh)
        s += *(const f32x4*)&g_part[(size_t)hh * SEQ * NDIM + idx];
    *(f32x4*)&out[idx] = s;
}

extern "C" void kernel_launch(void* const* d_in, const int* in_sizes, int n_in,
                              void* d_out, int out_size, void* d_ws, size_t ws_size,
                              hipStream_t stream) {
    detect_k <<<dim3(1),        dim3(256), 0, stream>>>((const unsigned short*)d_in[8]);
    convert_k<<<dim3(768, 10),  dim3(256), 0, stream>>>(d_in[0], d_in[1], d_in[2], d_in[3],
                                                        d_in[4], d_in[5], d_in[6], d_in[7],
                                                        d_in[8], d_in[9]);
    proj_nodes_kq <<<dim3(32, 32),  dim3(256), 0, stream>>>();
    proj_posrot_kq<<<dim3(8192),    dim3(256), 0, stream>>>();
    proj_v        <<<dim3(32, 192), dim3(256), 0, stream>>>();
    attn_k        <<<dim3(768),     dim3(512), 0, stream>>>();
    finalize_k    <<<dim3(512),     dim3(256), 0, stream>>>((float*)d_out);
}

// Round 12
// 333.679 us; speedup vs baseline: 1.5497x; 1.1536x over previous
//
#include <hip/hip_runtime.h>
#include <hip/hip_bf16.h>

typedef __bf16 bf16;
typedef __attribute__((ext_vector_type(8)))  __bf16 bf16x8;
typedef __attribute__((ext_vector_type(4)))  __bf16 bf16x4;
typedef __attribute__((ext_vector_type(4)))  float  f32x4;

#define SEQ   2048
#define NDIM  256
#define NH3   48
#define CH    64
#define SQS   72     // sQ row stride (pad: rows advance 4 banks)
#define SVS   72     // sV row stride
#define SPS   72     // sP row stride
#define VTS   2176   // g_vt row stride (4352B = 17 x 256B sectors)

// canonical bf16 input arena offsets (elements; multiples of 8 -> 16B aligned)
#define OFF_NODES 0
#define OFF_POS   524288
#define OFF_ROT   536576
#define OFF_WN    544768
#define OFF_BN    1069056
#define OFF_WP    1071104
#define OFF_BP    1083392
#define OFF_WR    1085440
#define OFF_WV    1093632
#define OFF_BV    4239360
#define TOT_IN    4251648

__device__ bf16  g_in[TOT_IN];              // 8.5 MB canonical bf16 inputs
__device__ bf16  g_k [NH3 * SEQ * CH];      // [h][s][c] 12.6 MB
__device__ bf16  g_q [NH3 * SEQ * CH];      // [h][s][c] 12.6 MB
__device__ bf16  g_vt[NH3 * NDIM * VTS];    // [h][d][j'] padded, j-permuted per 64-block
__device__ float g_part[(size_t)NH3 * SEQ * NDIM];  // 100 MB per-head partials (no atomics)
__device__ int   g_isf32;

// ---------------------------------------------------------------- dtype probe
__global__ __launch_bounds__(256) void detect_k(const unsigned short* __restrict__ p) {
    __shared__ int cff, czero;
    if (threadIdx.x == 0) { cff = 0; czero = 0; }
    __syncthreads();
    int ff = 0, zz = 0;
    for (int r = 0; r < 64; ++r) {
        int idx = threadIdx.x * 64 + r;
        unsigned short u = p[idx];
        if (((u >> 7) & 0xFF) == 0xFF) ff++;
        if (((idx & 1) == 0) && (u == 0)) zz++;
    }
    if (ff) atomicAdd(&cff, ff);
    if (zz) atomicAdd(&czero, zz);
    __syncthreads();
    if (threadIdx.x == 0) g_isf32 = (cff > 2 || czero > 6000) ? 1 : 0;
}

// --------------------------------------------------------- input canonicalize
__global__ __launch_bounds__(256) void convert_k(
    const void* s0, const void* s1, const void* s2, const void* s3, const void* s4,
    const void* s5, const void* s6, const void* s7, const void* s8, const void* s9)
{
    const void* srcs[10] = {s0, s1, s2, s3, s4, s5, s6, s7, s8, s9};
    const int   szs[10]  = {524288, 12288, 8192, 524288, 2048, 12288, 2048, 8192, 3145728, 12288};
    const int   offs[10] = {OFF_NODES, OFF_POS, OFF_ROT, OFF_WN, OFF_BN,
                            OFF_WP, OFF_BP, OFF_WR, OFF_WV, OFF_BV};
    const int y = blockIdx.y;
    const void* src = srcs[y];
    bf16* dst = g_in + offs[y];
    const int n = szs[y];
    const int isf = g_isf32;
    const int stride = gridDim.x * 256 * 4;
    for (int i = (blockIdx.x * 256 + threadIdx.x) * 4; i < n; i += stride) {
        bf16x4 o;
        if (isf) {
            float4 v = *(const float4*)((const float*)src + i);
            o[0] = (bf16)v.x; o[1] = (bf16)v.y; o[2] = (bf16)v.z; o[3] = (bf16)v.w;
        } else {
            o = *(const bf16x4*)((const bf16*)src + i);
        }
        *(bf16x4*)(dst + i) = o;
    }
}

// ------------------- nodes -> k,q (heads 0-15), XCD-swizzled (W L2 residency)
__global__ __launch_bounds__(256) void proj_nodes_kq()
{
    __shared__ __align__(16) bf16 sB[64 * 264];
    const bf16* nodes = g_in + OFF_NODES;
    const bf16* Wn    = g_in + OFF_WN;
    const bf16* bn    = g_in + OFF_BN;
    const int t    = threadIdx.x;
    const int bx   = blockIdx.x;          // 1024 blocks
    const int xcd  = bx & 7;
    const int rest = bx >> 3;             // 0..127
    const int f0   = (xcd * 4 + (rest & 3)) * 64;   // 4 f-blocks per XCD
    const int s0   = (rest >> 2) * 64;              // 0..31

    for (int rep = 0; rep < 8; ++rep) {
        int idx = t + rep * 256;
        int row = idx >> 5, chunk = idx & 31;
        *(bf16x8*)&sB[row * 264 + chunk * 8] =
            *(const bf16x8*)&Wn[(f0 + row) * 256 + chunk * 8];
    }
    __syncthreads();

    const int w = t >> 6, lane = t & 63;
    const int l15 = lane & 15, quad = lane >> 4;

    f32x4 acc[4] = {{}, {}, {}, {}};
    const bf16* arow = nodes + (s0 + w * 16 + l15) * 256 + quad * 8;
#pragma unroll
    for (int kc = 0; kc < 8; ++kc) {
        bf16x8 af = *(const bf16x8*)(arow + kc * 32);
#pragma unroll
        for (int ft = 0; ft < 4; ++ft) {
            bf16x8 bfr = *(const bf16x8*)&sB[(ft * 16 + l15) * 264 + kc * 32 + quad * 8];
            acc[ft] = __builtin_amdgcn_mfma_f32_16x16x32_bf16(af, bfr, acc[ft], 0, 0, 0);
        }
    }
#pragma unroll
    for (int ft = 0; ft < 4; ++ft) {
        int f = f0 + ft * 16 + l15;
        float bias = (float)bn[f];
        int h = f >> 7, c2 = f & 127;
        bf16* base = (c2 < 64) ? (g_k + h * SEQ * CH + c2)
                               : (g_q + h * SEQ * CH + (c2 - 64));
#pragma unroll
        for (int r = 0; r < 4; ++r) {
            int s = s0 + w * 16 + quad * 4 + r;
            base[s * CH] = (bf16)(acc[ft][r] + bias);
        }
    }
}

// ----------------- pos/rot -> k,q (heads 16-31 / 32-47), 4 outputs per thread
__global__ __launch_bounds__(256) void proj_posrot_kq()
{
    const bf16* pos  = g_in + OFF_POS;
    const bf16* rotq = g_in + OFF_ROT;
    const bf16* Wp   = g_in + OFF_WP;
    const bf16* bp   = g_in + OFF_BP;
    const bf16* Wr   = g_in + OFF_WR;
    int id = blockIdx.x * 256 + threadIdx.x;  // 2 * 2048 * 512
    int fg  = id & 511;                        // f-group of 4
    int s   = (id >> 9) & 2047;
    int src = id >> 20;
    int f0  = fg * 4;
    float y[4]; int h;
    if (src == 0) {
#pragma unroll
        for (int j = 0; j < 4; ++j) {
            float a = (float)bp[f0 + j];
#pragma unroll
            for (int x = 0; x < 6; ++x)
                a += (float)pos[s * 6 + x] * (float)Wp[(f0 + j) * 6 + x];
            y[j] = a;
        }
        h = 16 + (f0 >> 7);
    } else {
#pragma unroll
        for (int j = 0; j < 4; ++j) {
            float a = 0.f;
#pragma unroll
            for (int x = 0; x < 4; ++x)
                a += (float)rotq[s * 4 + x] * (float)Wr[(f0 + j) * 4 + x];
            y[j] = a;
        }
        h = 32 + (f0 >> 7);
    }
    bf16x4 o;
#pragma unroll
    for (int j = 0; j < 4; ++j) o[j] = (bf16)y[j];
    int c2 = f0 & 127;
    if (c2 < 64) *(bf16x4*)&g_k[(h * SEQ + s) * CH + c2]        = o;
    else         *(bf16x4*)&g_q[(h * SEQ + s) * CH + (c2 - 64)] = o;
}

// -------- nodes -> V (transposed + j-permuted, padded stride), XCD-swizzled
__global__ __launch_bounds__(256) void proj_v()
{
    __shared__ __align__(16) bf16 sB[64 * 264];
    __shared__ __align__(16) bf16 sO[64 * 72];
    const bf16* nodes = g_in + OFF_NODES;
    const bf16* Wv    = g_in + OFF_WV;
    const bf16* bv    = g_in + OFF_BV;
    const int t    = threadIdx.x;
    const int bx   = blockIdx.x;          // 6144 blocks
    const int xcd  = bx & 7;
    const int rest = bx >> 3;             // 0..767
    const int f0   = (xcd * 24 + (rest % 24)) * 64;  // 24 f-blocks per XCD (768KB W)
    const int s0   = (rest / 24) * 64;               // 0..31

    for (int rep = 0; rep < 8; ++rep) {
        int idx = t + rep * 256;
        int row = idx >> 5, chunk = idx & 31;
        *(bf16x8*)&sB[row * 264 + chunk * 8] =
            *(const bf16x8*)&Wv[(size_t)(f0 + row) * 256 + chunk * 8];
    }
    __syncthreads();

    const int w = t >> 6, lane = t & 63;
    const int l15 = lane & 15, quad = lane >> 4;

    f32x4 acc[4] = {{}, {}, {}, {}};
    const bf16* arow = nodes + (s0 + w * 16 + l15) * 256 + quad * 8;
#pragma unroll
    for (int kc = 0; kc < 8; ++kc) {
        bf16x8 af = *(const bf16x8*)(arow + kc * 32);
#pragma unroll
        for (int ft = 0; ft < 4; ++ft) {
            bf16x8 bfr = *(const bf16x8*)&sB[(ft * 16 + l15) * 264 + kc * 32 + quad * 8];
            acc[ft] = __builtin_amdgcn_mfma_f32_16x16x32_bf16(af, bfr, acc[ft], 0, 0, 0);
        }
    }
    __syncthreads();
#pragma unroll
    for (int ft = 0; ft < 4; ++ft) {
        int n = f0 + ft * 16 + l15;
        float bias = (float)bv[n];
#pragma unroll
        for (int r = 0; r < 4; ++r) {
            // s-local l = w*16+quad*4+r -> j' = (quad*4+r)*4 + w
            sO[(ft * 16 + l15) * 72 + (quad * 4 + r) * 4 + w] = (bf16)(acc[ft][r] + bias);
        }
    }
    __syncthreads();
    for (int rep = 0; rep < 2; ++rep) {
        int idx = t + rep * 256;
        int row = idx >> 3, chunk = idx & 7;
        *(bf16x8*)&g_vt[(size_t)(f0 + row) * VTS + s0 + chunk * 8] =
            *(const bf16x8*)&sO[row * 72 + chunk * 8];
    }
}

// ------------------------------------------------------------- attention
// R11 structure (512 thr, Bi=128, XCD head-clustering, coalesced staging,
// padded LDS strides, plain partial-plane stores). Change: next-step global
// loads are ISSUED right after B2 and their vmcnt drain lands at B3, covered
// by the PV MFMA phase; the B3->(top)B1 window is then pure ds_writes.
__global__ __launch_bounds__(512, 4) void attn_k()
{
    const int bx  = blockIdx.x;
    const int xcd = bx & 7;
    const int sub = bx >> 3;             // 0..95
    const int h   = xcd * 6 + (sub % 6); // 6 heads per XCD
    const int it  = sub / 6;             // 0..15
    const int i0  = it * 128;
    const int t   = threadIdx.x;
    const int w   = t >> 6, lane = t & 63;
    const int l15 = lane & 15, quad = lane >> 4;
    const bool rot = (h >= 32);

    __shared__ __align__(16) bf16 sQ[64 * SQS];      //  9216 B
    __shared__ __align__(16) bf16 sV[256 * SVS];     // 36864 B
    __shared__ __align__(16) bf16 sP[128 * SPS];     // 18432 B
    __shared__ float sL[128];                        //   512 B (total 65024)

    const bf16* kb = g_k  + h * SEQ * CH;
    const bf16* qb = g_q  + h * SEQ * CH;
    const bf16* vb = g_vt + (size_t)h * NDIM * VTS;

    // K fragments: wave w owns S-rows i0 + w*16 .. +16
    bf16x8 kf0 = *(const bf16x8*)&kb[(i0 + w * 16 + l15) * CH + quad * 8];
    bf16x8 kf1 = *(const bf16x8*)&kb[(i0 + w * 16 + l15) * CH + 32 + quad * 8];

    // PV split: i-half ih = w>>2 (64 rows), d-quarter dq = w&3 (64 cols)
    const int ih = w >> 2, dq = w & 3;

    // staging decomposition (16B chunks)
    const int qrow = t >> 3, qch = t & 7;

    f32x4 acc[4][4];
#pragma unroll
    for (int a = 0; a < 4; ++a)
#pragma unroll
        for (int b = 0; b < 4; ++b) acc[a][b] = (f32x4){0.f, 0.f, 0.f, 0.f};
    f32x4 lp = {0.f, 0.f, 0.f, 0.f};

    // prefetch step 0 into regs
    bf16x8 qpre, vpre[4];
    qpre = *(const bf16x8*)&qb[t * 8];
#pragma unroll
    for (int rep = 0; rep < 4; ++rep) {
        int idx = t + rep * 512;
        vpre[rep] = *(const bf16x8*)&vb[(size_t)(idx >> 3) * VTS + (idx & 7) * 8];
    }
    // write step 0 to LDS
    *(bf16x8*)&sQ[qrow * SQS + qch * 8] = qpre;
#pragma unroll
    for (int rep = 0; rep < 4; ++rep) {
        int idx = t + rep * 512;
        *(bf16x8*)&sV[(idx >> 3) * SVS + (idx & 7) * 8] = vpre[rep];
    }
    __syncthreads();                                   // B1 (step 0)

    for (int st = 0; st < 32; ++st) {
        // ---- S phase: 16 i-rows x 64 j per wave
        f32x4 sjb[4];
#pragma unroll
        for (int jb = 0; jb < 4; ++jb) {
            bf16x8 q0 = *(const bf16x8*)&sQ[(jb * 16 + l15) * SQS + quad * 8];
            bf16x8 q1 = *(const bf16x8*)&sQ[(jb * 16 + l15) * SQS + 32 + quad * 8];
            f32x4 sa = {};
            sa = __builtin_amdgcn_mfma_f32_16x16x32_bf16(kf0, q0, sa, 0, 0, 0);
            sa = __builtin_amdgcn_mfma_f32_16x16x32_bf16(kf1, q1, sa, 0, 0, 0);
            sjb[jb] = sa;
        }

        // ---- P phase: exp + pack; column j' = l15*4 + jb (logical j = jb*16+l15)
#pragma unroll
        for (int r = 0; r < 4; ++r) {
            bf16x4 pk;
#pragma unroll
            for (int jb = 0; jb < 4; ++jb) {
                float d = sjb[jb][r];
                float x = rot ? (d * d * 0.25f) : (d * 0.25f);
                x = fminf(x, 60.f);
                float p = __expf(x);
                lp[r] += p;
                pk[jb] = (bf16)p;
            }
            *(bf16x4*)&sP[(w * 16 + quad * 4 + r) * SPS + l15 * 4] = pk;
        }
        __syncthreads();                               // B2: sP visible

        // ---- issue next step's global loads (drain at B3, covered by PV)
        if (st < 31) {
            const bf16* qn = qb + (st + 1) * 4096;
            const bf16* vn = vb + (st + 1) * 64;
            qpre = *(const bf16x8*)&qn[t * 8];
#pragma unroll
            for (int rep = 0; rep < 4; ++rep) {
                int idx = t + rep * 512;
                vpre[rep] = *(const bf16x8*)&vn[(size_t)(idx >> 3) * VTS + (idx & 7) * 8];
            }
        }

        // ---- PV phase: wave w owns (ih, dq): 64 i x 64 d
#pragma unroll
        for (int kc = 0; kc < 2; ++kc) {
            bf16x8 ap[4], vf[4];
#pragma unroll
            for (int itr = 0; itr < 4; ++itr)
                ap[itr] = *(const bf16x8*)&sP[(ih * 64 + itr * 16 + l15) * SPS + kc * 32 + quad * 8];
#pragma unroll
            for (int dt = 0; dt < 4; ++dt)
                vf[dt] = *(const bf16x8*)&sV[(dq * 64 + dt * 16 + l15) * SVS + kc * 32 + quad * 8];
#pragma unroll
            for (int itr = 0; itr < 4; ++itr)
#pragma unroll
                for (int dt = 0; dt < 4; ++dt)
                    acc[itr][dt] = __builtin_amdgcn_mfma_f32_16x16x32_bf16(
                        ap[itr], vf[dt], acc[itr][dt], 0, 0, 0);
        }
        __syncthreads();                               // B3: all LDS reads done

        // ---- write staged regs for next step
        if (st < 31) {
            *(bf16x8*)&sQ[qrow * SQS + qch * 8] = qpre;
#pragma unroll
            for (int rep = 0; rep < 4; ++rep) {
                int idx = t + rep * 512;
                *(bf16x8*)&sV[(idx >> 3) * SVS + (idx & 7) * 8] = vpre[rep];
            }
            __syncthreads();                           // B1: staging visible
        }
    }

    // l reduce across the 16 j-lanes (wave w owns S-rows w*16..+16)
#pragma unroll
    for (int off = 1; off < 16; off <<= 1) {
#pragma unroll
        for (int r = 0; r < 4; ++r) lp[r] += __shfl_xor(lp[r], off, 64);
    }
    if (l15 == 0) *(f32x4*)&sL[w * 16 + quad * 4] = lp;
    __syncthreads();

    // normalize + plain stores into this head's private partial plane
    float* pb = g_part + (size_t)h * SEQ * NDIM;
#pragma unroll
    for (int itr = 0; itr < 4; ++itr) {
        f32x4 lv = *(const f32x4*)&sL[ih * 64 + itr * 16 + quad * 4];
#pragma unroll
        for (int r = 0; r < 4; ++r) {
            float inv = 1.0f / lv[r];
            float* ob = &pb[(size_t)(i0 + ih * 64 + itr * 16 + quad * 4 + r) * NDIM + dq * 64 + l15];
#pragma unroll
            for (int dt = 0; dt < 4; ++dt)
                ob[dt * 16] = acc[itr][dt][r] * inv;
        }
    }
}

// ------------------------------------------- finalize: sum 48 head planes
__global__ __launch_bounds__(256) void finalize_k(float* __restrict__ out) {
    int idx = (blockIdx.x * 256 + threadIdx.x) * 4;
    f32x4 s = {0.f, 0.f, 0.f, 0.f};
#pragma unroll
    for (int hh = 0; hh < NH3; ++hh)
        s += *(const f32x4*)&g_part[(size_t)hh * SEQ * NDIM + idx];
    *(f32x4*)&out[idx] = s;
}

extern "C" void kernel_launch(void* const* d_in, const int* in_sizes, int n_in,
                              void* d_out, int out_size, void* d_ws, size_t ws_size,
                              hipStream_t stream) {
    detect_k <<<dim3(1),        dim3(256), 0, stream>>>((const unsigned short*)d_in[8]);
    convert_k<<<dim3(768, 10),  dim3(256), 0, stream>>>(d_in[0], d_in[1], d_in[2], d_in[3],
                                                        d_in[4], d_in[5], d_in[6], d_in[7],
                                                        d_in[8], d_in[9]);
    proj_nodes_kq <<<dim3(1024),  dim3(256), 0, stream>>>();
    proj_posrot_kq<<<dim3(8192),  dim3(256), 0, stream>>>();
    proj_v        <<<dim3(6144),  dim3(256), 0, stream>>>();
    attn_k        <<<dim3(768),   dim3(512), 0, stream>>>();
    finalize_k    <<<dim3(512),   dim3(256), 0, stream>>>((float*)d_out);
}